// Round 1
// 611.047 us; speedup vs baseline: 1.1447x; 1.1447x over previous
//
#include <hip/hip_runtime.h>
#include <hip/hip_bf16.h>

// Rel_Transformer_Layer on MI355X gfx950.
// ROUND 5: fused flash-style attention. The score GEMM (K=128, 4 unpipelined
// k-steps, scalar epilogue) ran at 43 TF / 6.5% MfmaUtil and the attention path
// (score gemm + softmax + PV gemm + 64 MB scores traffic) cost ~280 us.
// Replaced by one fused kernel: 256 blocks (32 q-tiles x 8 heads), 4 waves,
// online softmax wave-local, P round-trip through per-wave LDS, O in registers.
// fp32 at the boundary, bf16 MFMA internally. d_ws unused; all scratch in d_out.

typedef unsigned short u16;
typedef short v8s __attribute__((ext_vector_type(8)));
typedef float v4f __attribute__((ext_vector_type(4)));

#define NTOK 2048
#define DMODEL 1024
#define NHEAD 8
#define DKH 128
#define FFDIM 4096
#define ATT_SCALE 0.08838834764831845f

__device__ __forceinline__ float b2f(u16 u) {
  union { unsigned int i; float f; } v; v.i = ((unsigned int)u) << 16; return v.f;
}
__device__ __forceinline__ u16 f2b(float f) {
  unsigned int x = __float_as_uint(f);
  x = x + 0x7FFFu + ((x >> 16) & 1u);   // RNE
  return (u16)(x >> 16);
}

// xb = bf16(x + in_deg_emb[in_degree] + out_deg_emb[out_degree]); all fp32 in
__global__ __launch_bounds__(256)
void prep_x(const float* __restrict__ x, const int* __restrict__ ind, const int* __restrict__ outd,
            const float* __restrict__ iw, const float* __restrict__ ow, u16* __restrict__ xb)
{
  const int n = blockIdx.x, t = threadIdx.x;
  const int a = ind[n], c = outd[n];
  const size_t o = (size_t)n * DMODEL + t * 4;
  float4 xv = *(const float4*)(x + o);
  float4 av = *(const float4*)(iw + (size_t)a * DMODEL + t * 4);
  float4 cv = *(const float4*)(ow + (size_t)c * DMODEL + t * 4);
  ushort4 ob;
  ob.x = f2b(xv.x + av.x + cv.x);
  ob.y = f2b(xv.y + av.y + cv.y);
  ob.z = f2b(xv.z + av.z + cv.z);
  ob.w = f2b(xv.w + av.w + cv.w);
  *(ushort4*)(xb + o) = ob;
}

// etw[r] = scale * sum_d rel_emb[r,d]*rel_weight[r,d]  (fp32 in)
__global__ void etw_k(const float* __restrict__ re, const float* __restrict__ rw, float* __restrict__ etw)
{
  const int r = threadIdx.x;
  if (r < 64) {
    float s = 0.f;
    for (int d = 0; d < DKH; d++) s += re[r * DKH + d] * rw[r * DKH + d];
    etw[r] = s * ATT_SCALE;
  }
}

// pack 6 fp32 bias vectors -> bf16: [bq 1024][bk 1024][bv 1024][bo 1024][b1 4096][b2 1024]
__global__ __launch_bounds__(256)
void pack_biases(const float* bq, const float* bk, const float* bv,
                 const float* bo, const float* b1, const float* b2, u16* __restrict__ dst)
{
  const int i = blockIdx.x * 256 + threadIdx.x;   // 10240 total
  float v;
  if      (i < 1024) v = bq[i];
  else if (i < 2048) v = bk[i - 1024];
  else if (i < 3072) v = bv[i - 2048];
  else if (i < 4096) v = bo[i - 3072];
  else if (i < 8192) v = b1[i - 4096];
  else               v = b2[i - 8192];
  dst[i] = f2b(v);
}

// bias2d[n,m] = bf16( sum_l etw[pet[n,m,l]]*paw[n,m,l] + path_len_emb[dist[n,m]] )
__global__ __launch_bounds__(256)
void bias2d_k(const int* __restrict__ pet, const float* __restrict__ paw,
              const int* __restrict__ dist, const float* __restrict__ etw,
              const float* __restrict__ plen, u16* __restrict__ out)
{
  __shared__ float se[64], sd[16];
  const int t = threadIdx.x;
  if (t < 64) se[t] = etw[t];
  if (t < 16) sd[t] = plen[t];
  __syncthreads();
  const size_t idx = (size_t)blockIdx.x * 256 + t;
  int4 p = ((const int4*)pet)[idx];
  float4 w = ((const float4*)paw)[idx];
  float s = se[p.x] * w.x + se[p.y] * w.y + se[p.z] * w.z + se[p.w] * w.w;
  s += sd[dist[idx]];
  out[idx] = f2b(s);
}

// transpose-convert: src fp32 [R][C] -> dst bf16 [C][R]; block (32,8), grid (C/32, R/32)
__global__ __launch_bounds__(256)
void tc2d(const float* __restrict__ src, u16* __restrict__ dst, int R, int C)
{
  __shared__ float tile[32][33];
  const int c0 = blockIdx.x * 32, r0 = blockIdx.y * 32;
  const int tx = threadIdx.x, ty = threadIdx.y;
#pragma unroll
  for (int j = 0; j < 32; j += 8) tile[ty + j][tx] = src[(size_t)(r0 + ty + j) * C + c0 + tx];
  __syncthreads();
#pragma unroll
  for (int j = 0; j < 32; j += 8) dst[(size_t)(c0 + ty + j) * R + r0 + tx] = f2b(tile[tx][ty + j]);
}

// bf16 transpose, z-batched: src [z][R][C] -> dst [z][C][R]; block (32,8)
__global__ __launch_bounds__(256)
void transpose2d(const u16* __restrict__ src, u16* __restrict__ dst, int R, int C)
{
  __shared__ u16 tile[32][33];
  const size_t zo = (size_t)blockIdx.z * R * C;
  const int c0 = blockIdx.x * 32, r0 = blockIdx.y * 32;
  const int tx = threadIdx.x, ty = threadIdx.y;
#pragma unroll
  for (int j = 0; j < 32; j += 8) tile[ty + j][tx] = src[zo + (size_t)(r0 + ty + j) * C + c0 + tx];
  __syncthreads();
#pragma unroll
  for (int j = 0; j < 32; j += 8) dst[zo + (size_t)(c0 + ty + j) * R + r0 + tx] = tile[tx][ty + j];
}

// LN(base+add)*g+b ; base/add bf16, g/b fp32; writes outb (bf16) and/or outf (fp32)
__global__ __launch_bounds__(256)
void resid_ln(const u16* __restrict__ base, const u16* __restrict__ add,
              const float* __restrict__ g, const float* __restrict__ b,
              u16* __restrict__ outb, float* __restrict__ outf)
{
  const size_t o = (size_t)blockIdx.x * DMODEL;
  const int t = threadIdx.x;
  ushort4 x4 = *(const ushort4*)(base + o + t * 4);
  ushort4 a4 = *(const ushort4*)(add + o + t * 4);
  float v[4] = { b2f(x4.x) + b2f(a4.x), b2f(x4.y) + b2f(a4.y),
                 b2f(x4.z) + b2f(a4.z), b2f(x4.w) + b2f(a4.w) };
  float s = v[0] + v[1] + v[2] + v[3];
  float sq = v[0] * v[0] + v[1] * v[1] + v[2] * v[2] + v[3] * v[3];
#pragma unroll
  for (int off = 32; off > 0; off >>= 1) { s += __shfl_xor(s, off, 64); sq += __shfl_xor(sq, off, 64); }
  __shared__ float rs[4], rq[4];
  if ((t & 63) == 0) { rs[t >> 6] = s; rq[t >> 6] = sq; }
  __syncthreads();
  s = rs[0] + rs[1] + rs[2] + rs[3];
  sq = rq[0] + rq[1] + rq[2] + rq[3];
  const float mean = s * (1.f / DMODEL);
  const float var = sq * (1.f / DMODEL) - mean * mean;
  const float rstd = rsqrtf(var + 1e-5f);
  float4 gv = ((const float4*)g)[t];
  float4 bv = ((const float4*)b)[t];
  float y[4] = { (v[0] - mean) * rstd * gv.x + bv.x, (v[1] - mean) * rstd * gv.y + bv.y,
                 (v[2] - mean) * rstd * gv.z + bv.z, (v[3] - mean) * rstd * gv.w + bv.w };
  if (outb) {
    ushort4 ob; ob.x = f2b(y[0]); ob.y = f2b(y[1]); ob.z = f2b(y[2]); ob.w = f2b(y[3]);
    *(ushort4*)(outb + o + t * 4) = ob;
  }
  if (outf) ((float4*)(outf + o))[t] = make_float4(y[0], y[1], y[2], y[3]);
}

// ---------------- fused flash attention ----------------
// grid (32, 8): blockIdx.x = q-tile of 64 rows, blockIdx.y = head. 256 threads.
// q   [8][2048][128] bf16 (flat-reshape head split, row stride 128)
// kT  [8][2048][128] bf16 (K^T per head: row = kv index, col = dk)
// vT  [8][128][2048] bf16 (V^T per head: row = dk,  col = kv index)
// bias2d [2048][2048] bf16 (path2d + dist2d, scale already folded into etw path? no:
//                           bias2d holds path2d+dist2d; QK product scaled by ATT_SCALE here)
// o   [8][2048][128] bf16
__global__ __launch_bounds__(256)
void fused_attn(const u16* __restrict__ q, const u16* __restrict__ kT,
                const u16* __restrict__ vT, const u16* __restrict__ bias2d,
                u16* __restrict__ o)
{
  __shared__ u16 Ks[128][136];       // K-tile rows=kv, cols=dk   (pad 136: 68-dw stride, 2-way = free)
  __shared__ u16 Vs[128][136];       // V^T-tile rows=dk, cols=kv-offset
  __shared__ u16 Ps[4][16][136];     // per-wave P round-trip (C-layout write, A-frag read)
  const int t = threadIdx.x, w = t >> 6, l = t & 63, lo = l & 15, hi = l >> 4;
  const int h = blockIdx.y;
  const int q0 = blockIdx.x * 64;
  const size_t ho = (size_t)h * 262144;

  // Q held in registers as A-fragments: row = lo (wave's 16 q-rows), k = hi*8
  v8s af[4];
#pragma unroll
  for (int kb = 0; kb < 4; kb++)
    af[kb] = *(const v8s*)&q[ho + (size_t)(q0 + w * 16 + lo) * 128 + kb * 32 + hi * 8];

  float m[4], lsum[4];
  v4f oa[8];                         // O accum, C-layout: row = hi*4+r, col d = f*16+lo
#pragma unroll
  for (int r = 0; r < 4; r++) { m[r] = -1e30f; lsum[r] = 0.f; }
#pragma unroll
  for (int f = 0; f < 8; f++) oa[f] = (v4f){0.f, 0.f, 0.f, 0.f};

  const int sr = t >> 2, sc = (t & 3) * 8;       // cooperative staging pattern
  const int browbase = q0 + w * 16 + hi * 4;     // this lane's first q-row

  for (int kt = 0; kt < 16; kt++) {
    const int kv0 = kt * 128;
    // stage K-tile (32 KB) + V^T-tile (32 KB)
#pragma unroll
    for (int rr = 0; rr < 2; rr++) {
      const int r_ = sr + rr * 64;
#pragma unroll
      for (int cc = 0; cc < 4; cc++) {
        const int c_ = sc + cc * 32;
        *(v8s*)&Ks[r_][c_] = *(const v8s*)&kT[ho + (size_t)(kv0 + r_) * 128 + c_];
        *(v8s*)&Vs[r_][c_] = *(const v8s*)&vT[ho + (size_t)r_ * 2048 + kv0 + c_];
      }
    }
    __syncthreads();

    // S = Q * Ktile^T : per wave 16 rows x 128 cols (8 col-frags x 4 k-steps)
    v4f sa[8];
#pragma unroll
    for (int f = 0; f < 8; f++) sa[f] = (v4f){0.f, 0.f, 0.f, 0.f};
#pragma unroll
    for (int kb = 0; kb < 4; kb++)
#pragma unroll
      for (int f = 0; f < 8; f++) {
        v8s bf_ = *(const v8s*)&Ks[f * 16 + lo][kb * 32 + hi * 8];
        sa[f] = __builtin_amdgcn_mfma_f32_16x16x32_bf16(af[kb], bf_, sa[f], 0, 0, 0);
      }
    // scale + bias2d (C layout: row = browbase+r, col = kv0 + f*16+lo)
#pragma unroll
    for (int f = 0; f < 8; f++)
#pragma unroll
      for (int r = 0; r < 4; r++)
        sa[f][r] = sa[f][r] * ATT_SCALE +
                   b2f(bias2d[(size_t)(browbase + r) * 2048 + kv0 + f * 16 + lo]);

    // online softmax, wave-local: row stats live in a 16-lane lo-group
    float corr[4];
#pragma unroll
    for (int r = 0; r < 4; r++) {
      float x = sa[0][r];
#pragma unroll
      for (int f = 1; f < 8; f++) x = fmaxf(x, sa[f][r]);
#pragma unroll
      for (int off = 1; off < 16; off <<= 1) x = fmaxf(x, __shfl_xor(x, off, 64));
      const float mn = fmaxf(m[r], x);
      corr[r] = __expf(m[r] - mn);   // first tile: exp(-huge)=0, scales zero accum
      m[r] = mn;
      lsum[r] *= corr[r];
    }
#pragma unroll
    for (int f = 0; f < 8; f++)
#pragma unroll
      for (int r = 0; r < 4; r++) {
        oa[f][r] *= corr[r];
        const float p = __expf(sa[f][r] - m[r]);
        lsum[r] += p;                // lane-partial (8 cols/row/tile); reduced at end
        Ps[w][hi * 4 + r][f * 16 + lo] = f2b(p);
      }
    __syncthreads();                 // P-write -> cross-lane A-frag read ordering

    // O += P(16x128) * Vtile(128x128): A-frag from Ps, B-frag from Vs rows = d
#pragma unroll
    for (int mb = 0; mb < 4; mb++) {
      const v8s pa = *(const v8s*)&Ps[w][lo][mb * 32 + hi * 8];
#pragma unroll
      for (int f = 0; f < 8; f++) {
        const v8s vb = *(const v8s*)&Vs[f * 16 + lo][mb * 32 + hi * 8];
        oa[f] = __builtin_amdgcn_mfma_f32_16x16x32_bf16(pa, vb, oa[f], 0, 0, 0);
      }
    }
    __syncthreads();                 // Ks/Vs free for next tile's staging
  }

  // finish: reduce row-sums across the 16-lane group, normalize, store
#pragma unroll
  for (int r = 0; r < 4; r++) {
#pragma unroll
    for (int off = 1; off < 16; off <<= 1) lsum[r] += __shfl_xor(lsum[r], off, 64);
    lsum[r] = 1.f / lsum[r];
  }
#pragma unroll
  for (int f = 0; f < 8; f++)
#pragma unroll
    for (int r = 0; r < 4; r++)
      o[ho + (size_t)(browbase + r) * 128 + f * 16 + lo] = f2b(oa[f][r] * lsum[r]);
}

// ---------------- MFMA GEMM: C = A[M,K] * Bt[N,K]^T (+ epilogue), bf16 in/out ----------------
#define EPI_BIAS  0   // + bias[col]
#define EPI_PLAIN 2   // plain

template<int EPI, bool RELU>
__global__ __launch_bounds__(256)
void gemm_bt(const u16* __restrict__ A, const u16* __restrict__ Bt,
             const u16* __restrict__ bias,
             u16* __restrict__ Cb,
             int M, int Nc, int K, int lda, int ldb, int ldc,
             long zA, long zB, long zC, long zBias)
{
  __shared__ u16 As[128 * 40];
  __shared__ u16 Bs[128 * 40];
  const int t = threadIdx.x;
  const int w = t >> 6, l = t & 63, lo = l & 15, hi = l >> 4;
  const int wm = (w >> 1) * 64, wn = (w & 1) * 64;
  const int row0 = blockIdx.x * 128, col0 = blockIdx.y * 128;
  A += (size_t)blockIdx.z * zA;
  Bt += (size_t)blockIdx.z * zB;
  const size_t coff = (size_t)blockIdx.z * zC;

  v4f acc[4][4];
#pragma unroll
  for (int i = 0; i < 4; i++)
#pragma unroll
    for (int j = 0; j < 4; j++) acc[i][j] = (v4f){0.f, 0.f, 0.f, 0.f};

  const int r0 = t >> 2, q0 = (t & 3) * 8;
  for (int k0 = 0; k0 < K; k0 += 32) {
    *(v8s*)&As[r0 * 40 + q0]        = *(const v8s*)&A[(size_t)(row0 + r0) * lda + k0 + q0];
    *(v8s*)&As[(r0 + 64) * 40 + q0] = *(const v8s*)&A[(size_t)(row0 + r0 + 64) * lda + k0 + q0];
    *(v8s*)&Bs[r0 * 40 + q0]        = *(const v8s*)&Bt[(size_t)(col0 + r0) * ldb + k0 + q0];
    *(v8s*)&Bs[(r0 + 64) * 40 + q0] = *(const v8s*)&Bt[(size_t)(col0 + r0 + 64) * ldb + k0 + q0];
    __syncthreads();
    v8s af[4], bfr[4];
#pragma unroll
    for (int i = 0; i < 4; i++) af[i] = *(const v8s*)&As[(wm + i * 16 + lo) * 40 + hi * 8];
#pragma unroll
    for (int j = 0; j < 4; j++) bfr[j] = *(const v8s*)&Bs[(wn + j * 16 + lo) * 40 + hi * 8];
#pragma unroll
    for (int i = 0; i < 4; i++)
#pragma unroll
      for (int j = 0; j < 4; j++)
        acc[i][j] = __builtin_amdgcn_mfma_f32_16x16x32_bf16(af[i], bfr[j], acc[i][j], 0, 0, 0);
    __syncthreads();
  }

  // C/D layout (m89-verified): col = lane&15, row = (lane>>4)*4 + reg
#pragma unroll
  for (int i = 0; i < 4; i++) {
#pragma unroll
    for (int j = 0; j < 4; j++) {
#pragma unroll
      for (int r = 0; r < 4; r++) {
        const int row = row0 + wm + i * 16 + hi * 4 + r;
        const int col = col0 + wn + j * 16 + lo;
        float v = acc[i][j][r];
        if (EPI == EPI_BIAS) v += b2f(bias[(size_t)blockIdx.z * zBias + col]);
        if (RELU) v = fmaxf(v, 0.f);
        Cb[coff + (size_t)row * ldc + col] = f2b(v);
      }
    }
  }
}

// ---------------- launch ----------------

extern "C" void kernel_launch(void* const* d_in, const int* in_sizes, int n_in,
                              void* d_out, int out_size, void* d_ws, size_t ws_size,
                              hipStream_t stream)
{
  const float* x    = (const float*)d_in[0];
  const float* lgx  = (const float*)d_in[1];
  const int*   ind  = (const int*)d_in[2];
  const int*   outd = (const int*)d_in[3];
  const int*   dist = (const int*)d_in[4];
  const int*   pet  = (const int*)d_in[5];
  const float* paw  = (const float*)d_in[6];
  const float* rele = (const float*)d_in[7];
  const float* relw = (const float*)d_in[8];
  const float* idegw = (const float*)d_in[9];
  const float* odegw = (const float*)d_in[10];
  const float* plen = (const float*)d_in[11];
  const float* Wq = (const float*)d_in[12]; const float* bq = (const float*)d_in[13];
  const float* Wk = (const float*)d_in[14]; const float* bk = (const float*)d_in[15];
  const float* Wv = (const float*)d_in[16]; const float* bv = (const float*)d_in[17];
  const float* Wo = (const float*)d_in[18]; const float* bo = (const float*)d_in[19];
  const float* ln1g = (const float*)d_in[20]; const float* ln1b = (const float*)d_in[21];
  const float* W1 = (const float*)d_in[22]; const float* b1 = (const float*)d_in[23];
  const float* W2 = (const float*)d_in[24]; const float* b2 = (const float*)d_in[25];
  const float* ln2g = (const float*)d_in[26]; const float* ln2b = (const float*)d_in[27];
  float* O = (float*)d_out;          // 18,874,368 fp32 elems = 75,497,472 B
  char*  B = (char*)d_out;

  // ---- byte-offset map inside d_out (d_ws UNUSED) ----
  u16*   WT     = (u16*)(B + 0);            // 2 MB: WoT slot
  float* etw    = (float*)(B + 2097152);    // 256 B
  u16*   biases = (u16*)(B + 2097408);      // 20,480 B: [bq|bk|bv|bo|b1|b2] bf16
  u16*   xb     = (u16*)(B + 8388608);      // 4 MB
  u16*   bias2d = (u16*)(B + 12582912);     // 8 MB bf16 [2048][2048]
  u16*   q      = (u16*)(B + 20971520);     // 4 MB [8][2048][128]
  u16*   k      = (u16*)(B + 25165824);     // 4 MB [8][128][2048]
  u16*   v      = (u16*)(B + 29360128);     // 4 MB [8][2048][128]
  u16*   kT     = (u16*)(B + 33554432);     // 4 MB [8][2048][128]
  u16*   vT     = (u16*)(B + 37748736);     // 4 MB [8][128][2048]
  u16*   WTqkv  = (u16*)(B + 41943040);     // 6 MB transient (dead after QKV gemm)
  u16*   obuf   = (u16*)(B + 41943040);     // 4 MB [8][2048][128] (written after WTqkv dead)
  // FFN phase (attention buffers dead):
  u16*   WoT  = WT;
  u16*   W1T  = kT;                          // 8 MB spanning kT+vT slots
  u16*   W2T  = kT;
  u16*   f1   = (u16*)(B + 46137344);        // 16 MB, ends at o2
  u16*   o2   = (u16*)(B + 62914560);        // 4 MB
  u16*   hb   = (u16*)(B + 67108864);        // 4 MB
  u16*   f2   = (u16*)(B + 71303168);        // 4 MB (last 4 MB of d_out)

  const dim3 tb(32, 8);

  prep_x<<<NTOK, 256, 0, stream>>>(x, ind, outd, idegw, odegw, xb);
  etw_k<<<1, 64, 0, stream>>>(rele, relw, etw);
  pack_biases<<<40, 256, 0, stream>>>(bq, bk, bv, bo, b1, b2, biases);
  bias2d_k<<<(NTOK * NTOK) / 256, 256, 0, stream>>>(pet, paw, dist, etw, plen, bias2d);

  // QKV: Wq/Wk/Wv -> bf16 transposed, then one z=3 batched GEMM
  tc2d<<<dim3(32, 32), tb, 0, stream>>>(Wq, WTqkv, 1024, 1024);
  tc2d<<<dim3(32, 32), tb, 0, stream>>>(Wk, WTqkv + 1048576, 1024, 1024);
  tc2d<<<dim3(32, 32), tb, 0, stream>>>(Wv, WTqkv + 2097152, 1024, 1024);
  gemm_bt<EPI_BIAS, false><<<dim3(16, 8, 3), 256, 0, stream>>>(
      xb, WTqkv, biases, q,
      2048, 1024, 1024, 1024, 1024, 1024,
      0L, 1048576L, 2097152L, 1024L);   // writes q,k,v (zC=2M elems apart)

  // k flat [8][128][2048] -> kT [8][2048][128]; v flat [8][2048][128] -> vT [8][128][2048]
  transpose2d<<<dim3(64, 4, 8), tb, 0, stream>>>(k, kT, 128, 2048);
  transpose2d<<<dim3(4, 64, 8), tb, 0, stream>>>(v, vT, 2048, 128);

  // fused attention: scores never touch HBM
  fused_attn<<<dim3(32, 8), 256, 0, stream>>>(q, kT, vT, bias2d, obuf);

  // o2 = obuf @ Wo + bo
  tc2d<<<dim3(32, 32), tb, 0, stream>>>(Wo, WoT, 1024, 1024);
  gemm_bt<EPI_BIAS, false><<<dim3(16, 8, 1), 256, 0, stream>>>(
      obuf, WoT, biases + 3072, o2,
      2048, 1024, 1024, 1024, 1024, 1024, 0L, 0L, 0L, 0L);

  // h = LN(xb + o2)
  resid_ln<<<NTOK, 256, 0, stream>>>(xb, o2, ln1g, ln1b, hb, nullptr);

  // f1 = relu(h @ W1 + b1)
  tc2d<<<dim3(128, 32), tb, 0, stream>>>(W1, W1T, 1024, 4096);
  gemm_bt<EPI_BIAS, true><<<dim3(16, 32, 1), 256, 0, stream>>>(
      hb, W1T, biases + 4096, f1,
      2048, 4096, 1024, 1024, 1024, 4096, 0L, 0L, 0L, 0L);

  // f2 = f1 @ W2 + b2
  tc2d<<<dim3(32, 128), tb, 0, stream>>>(W2, W2T, 4096, 1024);
  gemm_bt<EPI_BIAS, false><<<dim3(16, 8, 1), 256, 0, stream>>>(
      f1, W2T, biases + 8192, f2,
      2048, 1024, 4096, 4096, 4096, 1024, 0L, 0L, 0L, 0L);

  // out_x = LN(hb + f2) -> fp32 into d_out[0..8M)
  resid_ln<<<NTOK, 256, 0, stream>>>(hb, f2, ln2g, ln2b, nullptr, O);

  // lgx passthrough LAST (fp32, 64 MB; its region doubled as scratch above)
  hipMemcpyAsync(B + 8388608, lgx, 67108864ull, hipMemcpyDeviceToDevice, stream);
}

// Round 2
// 537.915 us; speedup vs baseline: 1.3004x; 1.1360x over previous
//
#include <hip/hip_runtime.h>
#include <hip/hip_bf16.h>

// Rel_Transformer_Layer on MI355X gfx950.
// ROUND 6: GEMM de-latencying. R5 counters: W2 gemm (128 blocks) at 99 us,
// Occupancy 5.5% (half the CUs idle, 1 wave/SIMD on the rest), ~1855 cyc/k-step
// vs ~300 cyc of real work -> exposed global latency. Fixes:
//  (a) reg-staged double-buffer in gemm_bt: prefetch next k-tile into regs
//      during MFMA; vmcnt wait moves off the critical path.
//  (b) split-K=2 for the two 128-block GEMMs (Wo, W2): 256 blocks fills all
//      CUs; fp32 partials in dead scratch + ksum2 reduce (bias there).
// fp32 at the boundary, bf16 MFMA internally. d_ws unused; all scratch in d_out.

typedef unsigned short u16;
typedef short v8s __attribute__((ext_vector_type(8)));
typedef float v4f __attribute__((ext_vector_type(4)));

#define NTOK 2048
#define DMODEL 1024
#define NHEAD 8
#define DKH 128
#define FFDIM 4096
#define ATT_SCALE 0.08838834764831845f

__device__ __forceinline__ float b2f(u16 u) {
  union { unsigned int i; float f; } v; v.i = ((unsigned int)u) << 16; return v.f;
}
__device__ __forceinline__ u16 f2b(float f) {
  unsigned int x = __float_as_uint(f);
  x = x + 0x7FFFu + ((x >> 16) & 1u);   // RNE
  return (u16)(x >> 16);
}

// xb = bf16(x + in_deg_emb[in_degree] + out_deg_emb[out_degree]); all fp32 in
__global__ __launch_bounds__(256)
void prep_x(const float* __restrict__ x, const int* __restrict__ ind, const int* __restrict__ outd,
            const float* __restrict__ iw, const float* __restrict__ ow, u16* __restrict__ xb)
{
  const int n = blockIdx.x, t = threadIdx.x;
  const int a = ind[n], c = outd[n];
  const size_t o = (size_t)n * DMODEL + t * 4;
  float4 xv = *(const float4*)(x + o);
  float4 av = *(const float4*)(iw + (size_t)a * DMODEL + t * 4);
  float4 cv = *(const float4*)(ow + (size_t)c * DMODEL + t * 4);
  ushort4 ob;
  ob.x = f2b(xv.x + av.x + cv.x);
  ob.y = f2b(xv.y + av.y + cv.y);
  ob.z = f2b(xv.z + av.z + cv.z);
  ob.w = f2b(xv.w + av.w + cv.w);
  *(ushort4*)(xb + o) = ob;
}

// etw[r] = scale * sum_d rel_emb[r,d]*rel_weight[r,d]  (fp32 in)
__global__ void etw_k(const float* __restrict__ re, const float* __restrict__ rw, float* __restrict__ etw)
{
  const int r = threadIdx.x;
  if (r < 64) {
    float s = 0.f;
    for (int d = 0; d < DKH; d++) s += re[r * DKH + d] * rw[r * DKH + d];
    etw[r] = s * ATT_SCALE;
  }
}

// pack 6 fp32 bias vectors -> bf16: [bq 1024][bk 1024][bv 1024][bo 1024][b1 4096][b2 1024]
__global__ __launch_bounds__(256)
void pack_biases(const float* bq, const float* bk, const float* bv,
                 const float* bo, const float* b1, const float* b2, u16* __restrict__ dst)
{
  const int i = blockIdx.x * 256 + threadIdx.x;   // 10240 total
  float v;
  if      (i < 1024) v = bq[i];
  else if (i < 2048) v = bk[i - 1024];
  else if (i < 3072) v = bv[i - 2048];
  else if (i < 4096) v = bo[i - 3072];
  else if (i < 8192) v = b1[i - 4096];
  else               v = b2[i - 8192];
  dst[i] = f2b(v);
}

// bias2d[n,m] = bf16( sum_l etw[pet[n,m,l]]*paw[n,m,l] + path_len_emb[dist[n,m]] )
__global__ __launch_bounds__(256)
void bias2d_k(const int* __restrict__ pet, const float* __restrict__ paw,
              const int* __restrict__ dist, const float* __restrict__ etw,
              const float* __restrict__ plen, u16* __restrict__ out)
{
  __shared__ float se[64], sd[16];
  const int t = threadIdx.x;
  if (t < 64) se[t] = etw[t];
  if (t < 16) sd[t] = plen[t];
  __syncthreads();
  const size_t idx = (size_t)blockIdx.x * 256 + t;
  int4 p = ((const int4*)pet)[idx];
  float4 w = ((const float4*)paw)[idx];
  float s = se[p.x] * w.x + se[p.y] * w.y + se[p.z] * w.z + se[p.w] * w.w;
  s += sd[dist[idx]];
  out[idx] = f2b(s);
}

// transpose-convert: src fp32 [R][C] -> dst bf16 [C][R]; block (32,8), grid (C/32, R/32)
__global__ __launch_bounds__(256)
void tc2d(const float* __restrict__ src, u16* __restrict__ dst, int R, int C)
{
  __shared__ float tile[32][33];
  const int c0 = blockIdx.x * 32, r0 = blockIdx.y * 32;
  const int tx = threadIdx.x, ty = threadIdx.y;
#pragma unroll
  for (int j = 0; j < 32; j += 8) tile[ty + j][tx] = src[(size_t)(r0 + ty + j) * C + c0 + tx];
  __syncthreads();
#pragma unroll
  for (int j = 0; j < 32; j += 8) dst[(size_t)(c0 + ty + j) * R + r0 + tx] = f2b(tile[tx][ty + j]);
}

// bf16 transpose, z-batched: src [z][R][C] -> dst [z][C][R]; block (32,8)
__global__ __launch_bounds__(256)
void transpose2d(const u16* __restrict__ src, u16* __restrict__ dst, int R, int C)
{
  __shared__ u16 tile[32][33];
  const size_t zo = (size_t)blockIdx.z * R * C;
  const int c0 = blockIdx.x * 32, r0 = blockIdx.y * 32;
  const int tx = threadIdx.x, ty = threadIdx.y;
#pragma unroll
  for (int j = 0; j < 32; j += 8) tile[ty + j][tx] = src[zo + (size_t)(r0 + ty + j) * C + c0 + tx];
  __syncthreads();
#pragma unroll
  for (int j = 0; j < 32; j += 8) dst[zo + (size_t)(c0 + ty + j) * R + r0 + tx] = tile[tx][ty + j];
}

// LN(base+add)*g+b ; base/add bf16, g/b fp32; writes outb (bf16) and/or outf (fp32)
__global__ __launch_bounds__(256)
void resid_ln(const u16* __restrict__ base, const u16* __restrict__ add,
              const float* __restrict__ g, const float* __restrict__ b,
              u16* __restrict__ outb, float* __restrict__ outf)
{
  const size_t o = (size_t)blockIdx.x * DMODEL;
  const int t = threadIdx.x;
  ushort4 x4 = *(const ushort4*)(base + o + t * 4);
  ushort4 a4 = *(const ushort4*)(add + o + t * 4);
  float v[4] = { b2f(x4.x) + b2f(a4.x), b2f(x4.y) + b2f(a4.y),
                 b2f(x4.z) + b2f(a4.z), b2f(x4.w) + b2f(a4.w) };
  float s = v[0] + v[1] + v[2] + v[3];
  float sq = v[0] * v[0] + v[1] * v[1] + v[2] * v[2] + v[3] * v[3];
#pragma unroll
  for (int off = 32; off > 0; off >>= 1) { s += __shfl_xor(s, off, 64); sq += __shfl_xor(sq, off, 64); }
  __shared__ float rs[4], rq[4];
  if ((t & 63) == 0) { rs[t >> 6] = s; rq[t >> 6] = sq; }
  __syncthreads();
  s = rs[0] + rs[1] + rs[2] + rs[3];
  sq = rq[0] + rq[1] + rq[2] + rq[3];
  const float mean = s * (1.f / DMODEL);
  const float var = sq * (1.f / DMODEL) - mean * mean;
  const float rstd = rsqrtf(var + 1e-5f);
  float4 gv = ((const float4*)g)[t];
  float4 bv = ((const float4*)b)[t];
  float y[4] = { (v[0] - mean) * rstd * gv.x + bv.x, (v[1] - mean) * rstd * gv.y + bv.y,
                 (v[2] - mean) * rstd * gv.z + bv.z, (v[3] - mean) * rstd * gv.w + bv.w };
  if (outb) {
    ushort4 ob; ob.x = f2b(y[0]); ob.y = f2b(y[1]); ob.z = f2b(y[2]); ob.w = f2b(y[3]);
    *(ushort4*)(outb + o + t * 4) = ob;
  }
  if (outf) ((float4*)(outf + o))[t] = make_float4(y[0], y[1], y[2], y[3]);
}

// ---------------- fused flash attention ----------------
// grid (32, 8): blockIdx.x = q-tile of 64 rows, blockIdx.y = head. 256 threads.
__global__ __launch_bounds__(256)
void fused_attn(const u16* __restrict__ q, const u16* __restrict__ kT,
                const u16* __restrict__ vT, const u16* __restrict__ bias2d,
                u16* __restrict__ o)
{
  __shared__ u16 Ks[128][136];       // K-tile rows=kv, cols=dk   (pad 136: 2-way = free)
  __shared__ u16 Vs[128][136];       // V^T-tile rows=dk, cols=kv-offset
  __shared__ u16 Ps[4][16][136];     // per-wave P round-trip (C-layout write, A-frag read)
  const int t = threadIdx.x, w = t >> 6, l = t & 63, lo = l & 15, hi = l >> 4;
  const int h = blockIdx.y;
  const int q0 = blockIdx.x * 64;
  const size_t ho = (size_t)h * 262144;

  // Q held in registers as A-fragments: row = lo (wave's 16 q-rows), k = hi*8
  v8s af[4];
#pragma unroll
  for (int kb = 0; kb < 4; kb++)
    af[kb] = *(const v8s*)&q[ho + (size_t)(q0 + w * 16 + lo) * 128 + kb * 32 + hi * 8];

  float m[4], lsum[4];
  v4f oa[8];                         // O accum, C-layout: row = hi*4+r, col d = f*16+lo
#pragma unroll
  for (int r = 0; r < 4; r++) { m[r] = -1e30f; lsum[r] = 0.f; }
#pragma unroll
  for (int f = 0; f < 8; f++) oa[f] = (v4f){0.f, 0.f, 0.f, 0.f};

  const int sr = t >> 2, sc = (t & 3) * 8;       // cooperative staging pattern
  const int browbase = q0 + w * 16 + hi * 4;     // this lane's first q-row

  for (int kt = 0; kt < 16; kt++) {
    const int kv0 = kt * 128;
#pragma unroll
    for (int rr = 0; rr < 2; rr++) {
      const int r_ = sr + rr * 64;
#pragma unroll
      for (int cc = 0; cc < 4; cc++) {
        const int c_ = sc + cc * 32;
        *(v8s*)&Ks[r_][c_] = *(const v8s*)&kT[ho + (size_t)(kv0 + r_) * 128 + c_];
        *(v8s*)&Vs[r_][c_] = *(const v8s*)&vT[ho + (size_t)r_ * 2048 + kv0 + c_];
      }
    }
    __syncthreads();

    // S = Q * Ktile^T : per wave 16 rows x 128 cols (8 col-frags x 4 k-steps)
    v4f sa[8];
#pragma unroll
    for (int f = 0; f < 8; f++) sa[f] = (v4f){0.f, 0.f, 0.f, 0.f};
#pragma unroll
    for (int kb = 0; kb < 4; kb++)
#pragma unroll
      for (int f = 0; f < 8; f++) {
        v8s bf_ = *(const v8s*)&Ks[f * 16 + lo][kb * 32 + hi * 8];
        sa[f] = __builtin_amdgcn_mfma_f32_16x16x32_bf16(af[kb], bf_, sa[f], 0, 0, 0);
      }
#pragma unroll
    for (int f = 0; f < 8; f++)
#pragma unroll
      for (int r = 0; r < 4; r++)
        sa[f][r] = sa[f][r] * ATT_SCALE +
                   b2f(bias2d[(size_t)(browbase + r) * 2048 + kv0 + f * 16 + lo]);

    // online softmax, wave-local: row stats live in a 16-lane lo-group
    float corr[4];
#pragma unroll
    for (int r = 0; r < 4; r++) {
      float x = sa[0][r];
#pragma unroll
      for (int f = 1; f < 8; f++) x = fmaxf(x, sa[f][r]);
#pragma unroll
      for (int off = 1; off < 16; off <<= 1) x = fmaxf(x, __shfl_xor(x, off, 64));
      const float mn = fmaxf(m[r], x);
      corr[r] = __expf(m[r] - mn);
      m[r] = mn;
      lsum[r] *= corr[r];
    }
#pragma unroll
    for (int f = 0; f < 8; f++)
#pragma unroll
      for (int r = 0; r < 4; r++) {
        oa[f][r] *= corr[r];
        const float p = __expf(sa[f][r] - m[r]);
        lsum[r] += p;
        Ps[w][hi * 4 + r][f * 16 + lo] = f2b(p);
      }
    __syncthreads();                 // P-write -> cross-lane A-frag read ordering

    // O += P(16x128) * Vtile(128x128)
#pragma unroll
    for (int mb = 0; mb < 4; mb++) {
      const v8s pa = *(const v8s*)&Ps[w][lo][mb * 32 + hi * 8];
#pragma unroll
      for (int f = 0; f < 8; f++) {
        const v8s vb = *(const v8s*)&Vs[f * 16 + lo][mb * 32 + hi * 8];
        oa[f] = __builtin_amdgcn_mfma_f32_16x16x32_bf16(pa, vb, oa[f], 0, 0, 0);
      }
    }
    __syncthreads();                 // Ks/Vs free for next tile's staging
  }

  // finish: reduce row-sums across the 16-lane group, normalize, store
#pragma unroll
  for (int r = 0; r < 4; r++) {
#pragma unroll
    for (int off = 1; off < 16; off <<= 1) lsum[r] += __shfl_xor(lsum[r], off, 64);
    lsum[r] = 1.f / lsum[r];
  }
#pragma unroll
  for (int f = 0; f < 8; f++)
#pragma unroll
    for (int r = 0; r < 4; r++)
      o[ho + (size_t)(browbase + r) * 128 + f * 16 + lo] = f2b(oa[f][r] * lsum[r]);
}

// ---------------- MFMA GEMM: C = A[M,K] * Bt[N,K]^T (+ epilogue), bf16 in ----------------
// Reg-staged double-buffer: next k-tile prefetched into regs during MFMA.
// KSPLIT>1: blockIdx.z = ks; fp32 partials (no epilogue) -> Cf[ks*M*ldc + ...].
#define EPI_BIAS  0   // + bias[col]
#define EPI_PLAIN 2   // plain

template<int EPI, bool RELU, int KSPLIT>
__global__ __launch_bounds__(256)
void gemm_bt(const u16* __restrict__ A, const u16* __restrict__ Bt,
             const u16* __restrict__ bias,
             u16* __restrict__ Cb, float* __restrict__ Cf,
             int M, int Nc, int K, int lda, int ldb, int ldc,
             long zA, long zB, long zC, long zBias)
{
  __shared__ u16 As[128 * 40];
  __shared__ u16 Bs[128 * 40];
  const int t = threadIdx.x;
  const int w = t >> 6, l = t & 63, lo = l & 15, hi = l >> 4;
  const int wm = (w >> 1) * 64, wn = (w & 1) * 64;
  const int row0 = blockIdx.x * 128, col0 = blockIdx.y * 128;
  const int zb = blockIdx.z / KSPLIT, ks = blockIdx.z % KSPLIT;
  const int klen = K / KSPLIT, kbeg = ks * klen;
  A += (size_t)zb * zA + kbeg;
  Bt += (size_t)zb * zB + kbeg;
  const size_t coff = (size_t)zb * zC;

  v4f acc[4][4];
#pragma unroll
  for (int i = 0; i < 4; i++)
#pragma unroll
    for (int j = 0; j < 4; j++) acc[i][j] = (v4f){0.f, 0.f, 0.f, 0.f};

  const int r0 = t >> 2, q0 = (t & 3) * 8;
  const u16* pa0 = A + (size_t)(row0 + r0) * lda + q0;
  const u16* pa1 = A + (size_t)(row0 + r0 + 64) * lda + q0;
  const u16* pb0 = Bt + (size_t)(col0 + r0) * ldb + q0;
  const u16* pb1 = Bt + (size_t)(col0 + r0 + 64) * ldb + q0;

  // prologue: stage tile 0 into regs
  v8s ra0 = *(const v8s*)pa0;
  v8s ra1 = *(const v8s*)pa1;
  v8s rb0 = *(const v8s*)pb0;
  v8s rb1 = *(const v8s*)pb1;

  for (int k0 = 0; k0 < klen; k0 += 32) {
    // write staged regs to LDS (vmcnt wait for prefetch lands here, off MFMA path)
    *(v8s*)&As[r0 * 40 + q0]        = ra0;
    *(v8s*)&As[(r0 + 64) * 40 + q0] = ra1;
    *(v8s*)&Bs[r0 * 40 + q0]        = rb0;
    *(v8s*)&Bs[(r0 + 64) * 40 + q0] = rb1;
    __syncthreads();
    // issue next tile's global loads; latency hides under ds_read + MFMA
    const int kn = k0 + 32;
    if (kn < klen) {
      ra0 = *(const v8s*)(pa0 + kn);
      ra1 = *(const v8s*)(pa1 + kn);
      rb0 = *(const v8s*)(pb0 + kn);
      rb1 = *(const v8s*)(pb1 + kn);
    }
    v8s af[4], bfr[4];
#pragma unroll
    for (int i = 0; i < 4; i++) af[i] = *(const v8s*)&As[(wm + i * 16 + lo) * 40 + hi * 8];
#pragma unroll
    for (int j = 0; j < 4; j++) bfr[j] = *(const v8s*)&Bs[(wn + j * 16 + lo) * 40 + hi * 8];
#pragma unroll
    for (int i = 0; i < 4; i++)
#pragma unroll
      for (int j = 0; j < 4; j++)
        acc[i][j] = __builtin_amdgcn_mfma_f32_16x16x32_bf16(af[i], bfr[j], acc[i][j], 0, 0, 0);
    __syncthreads();
  }

  // C/D layout (m89-verified): col = lane&15, row = (lane>>4)*4 + reg
  if (KSPLIT == 1) {
#pragma unroll
    for (int i = 0; i < 4; i++) {
#pragma unroll
      for (int j = 0; j < 4; j++) {
#pragma unroll
        for (int r = 0; r < 4; r++) {
          const int row = row0 + wm + i * 16 + hi * 4 + r;
          const int col = col0 + wn + j * 16 + lo;
          float v = acc[i][j][r];
          if (EPI == EPI_BIAS) v += b2f(bias[(size_t)zb * zBias + col]);
          if (RELU) v = fmaxf(v, 0.f);
          Cb[coff + (size_t)row * ldc + col] = f2b(v);
        }
      }
    }
  } else {
    float* P = Cf + (size_t)ks * M * ldc;
#pragma unroll
    for (int i = 0; i < 4; i++) {
#pragma unroll
      for (int j = 0; j < 4; j++) {
#pragma unroll
        for (int r = 0; r < 4; r++) {
          const int row = row0 + wm + i * 16 + hi * 4 + r;
          const int col = col0 + wn + j * 16 + lo;
          P[(size_t)row * ldc + col] = acc[i][j][r];
        }
      }
    }
  }
}

// out[idx] = f2b( p0[idx] + p1[idx] + bias[col] )  (optional relu); float4-wide
template<bool RELU>
__global__ __launch_bounds__(256)
void ksum2(const float* __restrict__ p0, const float* __restrict__ p1,
           const u16* __restrict__ bias, u16* __restrict__ out, int ncols)
{
  const size_t idx = (size_t)blockIdx.x * 256 + threadIdx.x;
  float4 a = ((const float4*)p0)[idx];
  float4 b = ((const float4*)p1)[idx];
  const int col = (int)((idx * 4) & (size_t)(ncols - 1));
  ushort4 bb = *(const ushort4*)(bias + col);
  float y0 = a.x + b.x + b2f(bb.x);
  float y1 = a.y + b.y + b2f(bb.y);
  float y2 = a.z + b.z + b2f(bb.z);
  float y3 = a.w + b.w + b2f(bb.w);
  if (RELU) { y0 = fmaxf(y0, 0.f); y1 = fmaxf(y1, 0.f); y2 = fmaxf(y2, 0.f); y3 = fmaxf(y3, 0.f); }
  ushort4 o4; o4.x = f2b(y0); o4.y = f2b(y1); o4.z = f2b(y2); o4.w = f2b(y3);
  ((ushort4*)out)[idx] = o4;
}

// ---------------- launch ----------------

extern "C" void kernel_launch(void* const* d_in, const int* in_sizes, int n_in,
                              void* d_out, int out_size, void* d_ws, size_t ws_size,
                              hipStream_t stream)
{
  const float* x    = (const float*)d_in[0];
  const float* lgx  = (const float*)d_in[1];
  const int*   ind  = (const int*)d_in[2];
  const int*   outd = (const int*)d_in[3];
  const int*   dist = (const int*)d_in[4];
  const int*   pet  = (const int*)d_in[5];
  const float* paw  = (const float*)d_in[6];
  const float* rele = (const float*)d_in[7];
  const float* relw = (const float*)d_in[8];
  const float* idegw = (const float*)d_in[9];
  const float* odegw = (const float*)d_in[10];
  const float* plen = (const float*)d_in[11];
  const float* Wq = (const float*)d_in[12]; const float* bq = (const float*)d_in[13];
  const float* Wk = (const float*)d_in[14]; const float* bk = (const float*)d_in[15];
  const float* Wv = (const float*)d_in[16]; const float* bv = (const float*)d_in[17];
  const float* Wo = (const float*)d_in[18]; const float* bo = (const float*)d_in[19];
  const float* ln1g = (const float*)d_in[20]; const float* ln1b = (const float*)d_in[21];
  const float* W1 = (const float*)d_in[22]; const float* b1 = (const float*)d_in[23];
  const float* W2 = (const float*)d_in[24]; const float* b2 = (const float*)d_in[25];
  const float* ln2g = (const float*)d_in[26]; const float* ln2b = (const float*)d_in[27];
  float* O = (float*)d_out;          // 18,874,368 fp32 elems = 75,497,472 B
  char*  B = (char*)d_out;

  // ---- byte-offset map inside d_out (d_ws UNUSED) ----
  u16*   WT     = (u16*)(B + 0);            // 2 MB: WoT slot
  float* etw    = (float*)(B + 2097152);    // 256 B
  u16*   biases = (u16*)(B + 2097408);      // 20,480 B: [bq|bk|bv|bo|b1|b2] bf16
  u16*   xb     = (u16*)(B + 8388608);      // 4 MB
  u16*   bias2d = (u16*)(B + 12582912);     // 8 MB bf16 [2048][2048]
  u16*   q      = (u16*)(B + 20971520);     // 4 MB [8][2048][128]
  u16*   k      = (u16*)(B + 25165824);     // 4 MB [8][128][2048]
  u16*   v      = (u16*)(B + 29360128);     // 4 MB [8][2048][128]
  u16*   kT     = (u16*)(B + 33554432);     // 4 MB [8][2048][128]
  u16*   vT     = (u16*)(B + 37748736);     // 4 MB [8][128][2048]
  u16*   WTqkv  = (u16*)(B + 41943040);     // 6 MB transient (dead after QKV gemm)
  u16*   obuf   = (u16*)(B + 41943040);     // 4 MB [8][2048][128] (after WTqkv dead)
  // post-attention phase (bias2d/q/k/v/kT/vT all dead):
  float* part0  = (float*)(B + 12582912);   // 8 MB fp32 [2048][1024] split-K partial 0
  float* part1  = (float*)(B + 20971520);   // 8 MB fp32 partial 1
  u16*   WoT  = WT;
  u16*   W1T  = kT;                          // 8 MB spanning kT+vT slots
  u16*   W2T  = kT;
  u16*   f1   = (u16*)(B + 46137344);        // 16 MB (44..60 MiB)
  u16*   o2   = (u16*)(B + 62914560);        // 4 MB
  u16*   hb   = (u16*)(B + 67108864);        // 4 MB
  u16*   f2   = (u16*)(B + 71303168);        // 4 MB (last 4 MB of d_out)

  const dim3 tb(32, 8);

  prep_x<<<NTOK, 256, 0, stream>>>(x, ind, outd, idegw, odegw, xb);
  etw_k<<<1, 64, 0, stream>>>(rele, relw, etw);
  pack_biases<<<40, 256, 0, stream>>>(bq, bk, bv, bo, b1, b2, biases);
  bias2d_k<<<(NTOK * NTOK) / 256, 256, 0, stream>>>(pet, paw, dist, etw, plen, bias2d);

  // QKV: Wq/Wk/Wv -> bf16 transposed, then one z=3 batched GEMM
  tc2d<<<dim3(32, 32), tb, 0, stream>>>(Wq, WTqkv, 1024, 1024);
  tc2d<<<dim3(32, 32), tb, 0, stream>>>(Wk, WTqkv + 1048576, 1024, 1024);
  tc2d<<<dim3(32, 32), tb, 0, stream>>>(Wv, WTqkv + 2097152, 1024, 1024);
  gemm_bt<EPI_BIAS, false, 1><<<dim3(16, 8, 3), 256, 0, stream>>>(
      xb, WTqkv, biases, q, nullptr,
      2048, 1024, 1024, 1024, 1024, 1024,
      0L, 1048576L, 2097152L, 1024L);   // writes q,k,v (zC=2M elems apart)

  // k flat [8][128][2048] -> kT [8][2048][128]; v flat [8][2048][128] -> vT [8][128][2048]
  transpose2d<<<dim3(64, 4, 8), tb, 0, stream>>>(k, kT, 128, 2048);
  transpose2d<<<dim3(4, 64, 8), tb, 0, stream>>>(v, vT, 2048, 128);

  // fused attention: scores never touch HBM
  fused_attn<<<dim3(32, 8), 256, 0, stream>>>(q, kT, vT, bias2d, obuf);

  // o2 = obuf @ Wo + bo   (split-K=2 -> 256 blocks; bias applied in reduce)
  tc2d<<<dim3(32, 32), tb, 0, stream>>>(Wo, WoT, 1024, 1024);
  gemm_bt<EPI_PLAIN, false, 2><<<dim3(16, 8, 2), 256, 0, stream>>>(
      obuf, WoT, nullptr, nullptr, part0,
      2048, 1024, 1024, 1024, 1024, 1024, 0L, 0L, 0L, 0L);
  ksum2<false><<<2048, 256, 0, stream>>>(part0, part1, biases + 3072, o2, 1024);

  // h = LN(xb + o2)
  resid_ln<<<NTOK, 256, 0, stream>>>(xb, o2, ln1g, ln1b, hb, nullptr);

  // f1 = relu(h @ W1 + b1)
  tc2d<<<dim3(128, 32), tb, 0, stream>>>(W1, W1T, 1024, 4096);
  gemm_bt<EPI_BIAS, true, 1><<<dim3(16, 32, 1), 256, 0, stream>>>(
      hb, W1T, biases + 4096, f1, nullptr,
      2048, 4096, 1024, 1024, 1024, 4096, 0L, 0L, 0L, 0L);

  // f2 = f1 @ W2 + b2   (split-K=2 over K=4096 -> 256 blocks)
  tc2d<<<dim3(32, 128), tb, 0, stream>>>(W2, W2T, 4096, 1024);
  gemm_bt<EPI_PLAIN, false, 2><<<dim3(16, 8, 2), 256, 0, stream>>>(
      f1, W2T, nullptr, nullptr, part0,
      2048, 1024, 4096, 4096, 4096, 1024, 0L, 0L, 0L, 0L);
  ksum2<false><<<2048, 256, 0, stream>>>(part0, part1, biases + 8192, f2, 1024);

  // out_x = LN(hb + f2) -> fp32 into d_out[0..8M)
  resid_ln<<<NTOK, 256, 0, stream>>>(hb, f2, ln2g, ln2b, nullptr, O);

  // lgx passthrough LAST (fp32, 64 MB; its region doubled as scratch above)
  hipMemcpyAsync(B + 8388608, lgx, 67108864ull, hipMemcpyDeviceToDevice, stream);
}